// Round 1
// baseline (9814.463 us; speedup 1.0000x reference)
//
#include <hip/hip_runtime.h>
#include <hip/hip_bf16.h>
#include <math.h>

// ---------- types ----------
typedef __attribute__((ext_vector_type(8))) __bf16 bf16x8;
typedef __attribute__((ext_vector_type(4))) float f32x4;
typedef __attribute__((ext_vector_type(4))) float f4v;
typedef __attribute__((ext_vector_type(8))) unsigned short us8;
typedef __attribute__((ext_vector_type(4))) unsigned short us4;

union BC8 { us8 u; bf16x8 b; };
__device__ __forceinline__ bf16x8 as_bf16x8(us8 u) { BC8 c; c.u = u; return c.b; }

__device__ __forceinline__ unsigned short f2bf(float f) {
    unsigned u = __float_as_uint(f);
    unsigned r = (u + 0x7FFFu + ((u >> 16) & 1u)) >> 16;   // RNE
    return (unsigned short)r;
}
__device__ __forceinline__ float bf2f(unsigned short h) {
    return __uint_as_float(((unsigned)h) << 16);
}

// ---------- fp32 -> bf16 convert (8 elems/thread) ----------
__global__ __launch_bounds__(256) void cvt_ker(const float* __restrict__ s,
                                               unsigned short* __restrict__ d, int n8) {
    const int i = blockIdx.x * 256 + threadIdx.x;
    if (i >= n8) return;
    const f4v* sp = (const f4v*)s + ((size_t)i << 1);
    f4v a = sp[0], b = sp[1];
    us8 o;
#pragma unroll
    for (int j = 0; j < 4; j++) { o[j] = f2bf(a[j]); o[j + 4] = f2bf(b[j]); }
    *(us8*)(d + ((size_t)i << 3)) = o;
}

// ---------- bf16 NT GEMM: C[r][n] = sum_k A[r][k]*B[n][k], bf16 out ----------
// 128x128 tile, BK=32, 4 waves (2x2 of 64x64), reg-staged LDS, single buffer.
// permute: output row gr=(t*32+b) -> orow = b*(M/32)+t
__global__ __launch_bounds__(256) void gemm_bt(const unsigned short* __restrict__ Amat,
                                               const unsigned short* __restrict__ Bmat,
                                               unsigned short* __restrict__ Cmat,
                                               int M, int N, int K, int permute) {
    const int nbn = N >> 7;
    const int bm = (blockIdx.x / nbn) << 7;
    const int bn = (blockIdx.x % nbn) << 7;
    const int tid = threadIdx.x;
    const int w = tid >> 6, l = tid & 63;
    const int wr = (w >> 1) << 6, wc = (w & 1) << 6;
    const int lo = l & 15, hi = l >> 4;

    __shared__ alignas(16) unsigned short As[128 * 32];
    __shared__ alignas(16) unsigned short Bs[128 * 32];

    f32x4 acc[4][4];
#pragma unroll
    for (int i = 0; i < 4; i++)
#pragma unroll
        for (int j = 0; j < 4; j++) acc[i][j] = (f32x4){0.f, 0.f, 0.f, 0.f};

    const int lin0 = tid, lin1 = 256 + tid;
    const int r0 = lin0 >> 2, c0 = (lin0 & 3) << 3;
    const int r1 = lin1 >> 2, c1 = (lin1 & 3) << 3;
    const size_t Kz = (size_t)K;

    us8 ra0 = *(const us8*)(Amat + (size_t)(bm + r0) * Kz + c0);
    us8 ra1 = *(const us8*)(Amat + (size_t)(bm + r1) * Kz + c1);
    us8 rb0 = *(const us8*)(Bmat + (size_t)(bn + r0) * Kz + c0);
    us8 rb1 = *(const us8*)(Bmat + (size_t)(bn + r1) * Kz + c1);

    const int NT = K >> 5;
    for (int kt = 0; kt < NT; ++kt) {
        __syncthreads();                       // previous tile's readers done
        *(us8*)(As + r0 * 32 + c0) = ra0;
        *(us8*)(As + r1 * 32 + c1) = ra1;
        *(us8*)(Bs + r0 * 32 + c0) = rb0;
        *(us8*)(Bs + r1 * 32 + c1) = rb1;
        __syncthreads();
        if (kt + 1 < NT) {                     // async prefetch next tile
            const int k0 = (kt + 1) << 5;
            ra0 = *(const us8*)(Amat + (size_t)(bm + r0) * Kz + k0 + c0);
            ra1 = *(const us8*)(Amat + (size_t)(bm + r1) * Kz + k0 + c1);
            rb0 = *(const us8*)(Bmat + (size_t)(bn + r0) * Kz + k0 + c0);
            rb1 = *(const us8*)(Bmat + (size_t)(bn + r1) * Kz + k0 + c1);
        }
        bf16x8 af[4], bfm[4];
#pragma unroll
        for (int mi = 0; mi < 4; ++mi)
            af[mi] = as_bf16x8(*(const us8*)(As + (wr + mi * 16 + lo) * 32 + hi * 8));
#pragma unroll
        for (int ni = 0; ni < 4; ++ni)
            bfm[ni] = as_bf16x8(*(const us8*)(Bs + (wc + ni * 16 + lo) * 32 + hi * 8));
#pragma unroll
        for (int mi = 0; mi < 4; ++mi)
#pragma unroll
            for (int ni = 0; ni < 4; ++ni)
                acc[mi][ni] = __builtin_amdgcn_mfma_f32_16x16x32_bf16(af[mi], bfm[ni], acc[mi][ni], 0, 0, 0);
    }

#pragma unroll
    for (int mi = 0; mi < 4; ++mi) {
#pragma unroll
        for (int r = 0; r < 4; ++r) {
            const int gr = bm + wr + mi * 16 + hi * 4 + r;
            const size_t orow = permute ? ((size_t)(gr & 31) * (size_t)(M >> 5) + (size_t)(gr >> 5))
                                        : (size_t)gr;
            unsigned short* crow = Cmat + orow * (size_t)N + bn + wc;
#pragma unroll
            for (int ni = 0; ni < 4; ++ni)
                crow[ni * 16 + lo] = f2bf(acc[mi][ni][r]);
        }
    }
}

// ---------- sequential scan: h = tanh(h@A^T + xb_t), persistent, 64 blocks ----------
#define NBLK 64
__global__ __launch_bounds__(128) void scan_ker(const unsigned short* __restrict__ Abf,
                                                const unsigned short* __restrict__ xb,
                                                unsigned short* __restrict__ hs,
                                                unsigned short* __restrict__ hbuf,
                                                unsigned* __restrict__ bar) {
    const int tid = threadIdx.x;
    const int w = tid >> 6, l = tid & 63;
    const int lo = l & 15, hi = l >> 4;
    const int n0 = blockIdx.x << 4;                 // 16 output cols per block

    __shared__ alignas(16) unsigned short Apan[16 * 1024];   // swizzled A panel, 32 KB

    // preload A panel rows n0..n0+15, XOR-swizzled to kill ds_read_b128 conflicts
    for (int idx = tid; idx < 2048; idx += 128) {
        const int row = idx >> 7;
        const int kb = (idx & 127) << 4;            // byte offset in row
        us8 v = *(const us8*)(Abf + (size_t)(n0 + row) * 1024 + ((idx & 127) << 3));
        *(us8*)((char*)Apan + row * 2048 + (kb ^ ((row & 7) << 4))) = v;
    }

    const int mA = (w << 4) + lo;                   // A-operand row (batch)
    const int mS0 = (w << 4) + (hi << 2);           // D-layout store row base
    const int nc = n0 + lo;                         // output column
    const int swb = (lo & 7) << 4;

    unsigned short xbv[4];
#pragma unroll
    for (int r = 0; r < 4; r++)                     // xb prefetch for t=0
        xbv[r] = xb[(size_t)(mS0 + r) * 1048576 + nc];
    __syncthreads();                                // A panel ready

    for (int t = 0; t < 1024; ++t) {
        const char* hbase = (const char*)hbuf + ((t & 1) << 16) + (size_t)mA * 2048 + (hi << 4);
        f32x4 acc0 = {0.f, 0.f, 0.f, 0.f}, acc1 = {0.f, 0.f, 0.f, 0.f};
        us8 afr[8];
#pragma unroll
        for (int i = 0; i < 8; i++) afr[i] = *(const us8*)(hbase + i * 64);   // pipeline depth 8
#pragma unroll
        for (int kk = 0; kk < 32; ++kk) {
            bf16x8 a = as_bf16x8(afr[kk & 7]);
            const int kbyte = (kk << 6) + (hi << 4);
            bf16x8 b = as_bf16x8(*(const us8*)((const char*)Apan + lo * 2048 + (kbyte ^ swb)));
            if (kk & 1) acc1 = __builtin_amdgcn_mfma_f32_16x16x32_bf16(a, b, acc1, 0, 0, 0);
            else        acc0 = __builtin_amdgcn_mfma_f32_16x16x32_bf16(a, b, acc0, 0, 0, 0);
            if (kk < 24) afr[kk & 7] = *(const us8*)(hbase + (kk + 8) * 64);
        }
        f32x4 acc = acc0 + acc1;

        unsigned short* hw = hbuf + (((t + 1) & 1) ? 32768 : 0);
#pragma unroll
        for (int r = 0; r < 4; r++) {
            const int m = mS0 + r;
            const float v = tanhf(acc[r] + bf2f(xbv[r]));
            const unsigned short hb = f2bf(v);
            hw[(size_t)m * 1024 + nc] = hb;                       // next-step h (dbuf)
            hs[((size_t)t * 32 + m) * 1024 + nc] = hb;            // history for C-proj
        }
        if (t < 1023) {
#pragma unroll
            for (int r = 0; r < 4; r++)                            // prefetch xb[t+1]
                xbv[r] = xb[(size_t)(mS0 + r) * 1048576 + (size_t)(t + 1) * 1024 + nc];
        }

        // release my h writes, arrive, wait for all 64 blocks, acquire
        __threadfence();
        __syncthreads();
        if (tid == 0) {
            __hip_atomic_fetch_add(bar, 1u, __ATOMIC_RELEASE, __HIP_MEMORY_SCOPE_AGENT);
            const unsigned tgt = (unsigned)NBLK * (unsigned)(t + 1);
            while (__hip_atomic_load(bar, __ATOMIC_ACQUIRE, __HIP_MEMORY_SCOPE_AGENT) < tgt) {}
        }
        __syncthreads();
        __threadfence();
    }
}

// ---------- fused add-x + LayerNorm, one wave per row ----------
__global__ __launch_bounds__(256) void ln_ker(const unsigned short* __restrict__ y,
                                              const float* __restrict__ x,
                                              const float* __restrict__ gamma,
                                              const float* __restrict__ beta,
                                              float* __restrict__ out) {
    const int row = (blockIdx.x << 2) + (threadIdx.x >> 6);
    const int l = threadIdx.x & 63;
    const unsigned short* yr = y + (size_t)row * 1024;
    const float* xr = x + (size_t)row * 1024;
    float v[16];
    float s = 0.f, s2 = 0.f;
#pragma unroll
    for (int j = 0; j < 4; j++) {
        const int e = ((j << 6) + l) << 2;
        f4v xv = *(const f4v*)(xr + e);
        us4 yv = *(const us4*)(yr + e);
#pragma unroll
        for (int i = 0; i < 4; i++) {
            float t = xv[i] + bf2f(yv[i]);
            v[(j << 2) + i] = t; s += t; s2 += t * t;
        }
    }
#pragma unroll
    for (int off = 1; off < 64; off <<= 1) {
        s += __shfl_xor(s, off, 64);
        s2 += __shfl_xor(s2, off, 64);
    }
    const float mu = s * (1.f / 1024.f);
    const float var = fmaxf(s2 * (1.f / 1024.f) - mu * mu, 0.f);
    const float rs = rsqrtf(var + 1e-5f);
#pragma unroll
    for (int j = 0; j < 4; j++) {
        const int e = ((j << 6) + l) << 2;
        f4v g = *(const f4v*)(gamma + e);
        f4v bt = *(const f4v*)(beta + e);
        f4v o;
#pragma unroll
        for (int i = 0; i < 4; i++) o[i] = (v[(j << 2) + i] - mu) * rs * g[i] + bt[i];
        *(f4v*)(out + (size_t)row * 1024 + e) = o;
    }
}

// ---------- launch ----------
extern "C" void kernel_launch(void* const* d_in, const int* in_sizes, int n_in,
                              void* d_out, int out_size, void* d_ws, size_t ws_size,
                              hipStream_t stream) {
    const float* x = (const float*)d_in[0];
    const float* Amat = (const float*)d_in[1];
    const float* Bmat = (const float*)d_in[2];
    const float* Cmat = (const float*)d_in[3];
    const float* gamma = (const float*)d_in[4];
    const float* beta = (const float*)d_in[5];
    float* out = (float*)d_out;
    char* ws = (char*)d_ws;

    // workspace layout
    const size_t R1 = 0;                       // x_bf16 (phase1) -> hs (phase2/3), 64 MiB
    const size_t R2 = 67108864;                // xb (phase1/2)   -> y tmp (phase3), 64 MiB
    const size_t OA = 134217728;               // A bf16, 2 MiB
    const size_t OB = OA + 2097152;            // B bf16
    const size_t OC = OB + 2097152;            // C bf16
    const size_t OH = OC + 2097152;            // h double buffer, 128 KiB
    const size_t OBAR = OH + 131072;           // barrier counter
    if (ws_size < OBAR + 256) return;

    unsigned short* xbf = (unsigned short*)(ws + R1);
    unsigned short* hsb = (unsigned short*)(ws + R1);
    unsigned short* xbb = (unsigned short*)(ws + R2);
    unsigned short* tmp = (unsigned short*)(ws + R2);
    unsigned short* Ab = (unsigned short*)(ws + OA);
    unsigned short* Bb = (unsigned short*)(ws + OB);
    unsigned short* Cb = (unsigned short*)(ws + OC);
    unsigned short* hbuf = (unsigned short*)(ws + OH);
    unsigned* bar = (unsigned*)(ws + OBAR);

    hipMemsetAsync(ws + OH, 0, 131072 + 256, stream);          // h0 = 0, barrier = 0

    cvt_ker<<<16384, 256, 0, stream>>>(x, xbf, 4194304);       // x -> bf16
    cvt_ker<<<512, 256, 0, stream>>>(Amat, Ab, 131072);
    cvt_ker<<<512, 256, 0, stream>>>(Bmat, Bb, 131072);
    cvt_ker<<<512, 256, 0, stream>>>(Cmat, Cb, 131072);

    // xb[b][s][e] = sum_d x[b][s][d]*B[e][d]
    gemm_bt<<<2048, 256, 0, stream>>>(xbf, Bb, xbb, 32768, 1024, 1024, 0);

    // sequential recurrence; writes hs[t][b][d]
    scan_ker<<<NBLK, 128, 0, stream>>>(Ab, xbb, hsb, hbuf, bar);

    // y[t*32+b][e] = sum_d hs[..][d]*C[e][d], stored permuted as tmp[b][s][e]
    gemm_bt<<<2048, 256, 0, stream>>>(hsb, Cb, tmp, 32768, 1024, 1024, 1);

    // out = LN(y + x)
    ln_ker<<<8192, 256, 0, stream>>>(tmp, x, gamma, beta, out);
}

// Round 2
// 6312.270 us; speedup vs baseline: 1.5548x; 1.5548x over previous
//
#include <hip/hip_runtime.h>
#include <hip/hip_bf16.h>
#include <math.h>

// ---------- types ----------
typedef __attribute__((ext_vector_type(8))) __bf16 bf16x8;
typedef __attribute__((ext_vector_type(4))) float f32x4;
typedef __attribute__((ext_vector_type(4))) float f4v;
typedef __attribute__((ext_vector_type(8))) unsigned short us8;
typedef __attribute__((ext_vector_type(4))) unsigned short us4;
typedef unsigned long long u64;

union BC8 { us8 u; bf16x8 b; u64 q[2]; };
__device__ __forceinline__ bf16x8 as_bf16x8(us8 u) { BC8 c; c.u = u; return c.b; }

__device__ __forceinline__ unsigned short f2bf(float f) {
    unsigned u = __float_as_uint(f);
    unsigned r = (u + 0x7FFFu + ((u >> 16) & 1u)) >> 16;   // RNE
    return (unsigned short)r;
}
__device__ __forceinline__ float bf2f(unsigned short h) {
    return __uint_as_float(((unsigned)h) << 16);
}

// ---------- fp32 -> bf16 convert (8 elems/thread) ----------
__global__ __launch_bounds__(256) void cvt_ker(const float* __restrict__ s,
                                               unsigned short* __restrict__ d, int n8) {
    const int i = blockIdx.x * 256 + threadIdx.x;
    if (i >= n8) return;
    const f4v* sp = (const f4v*)s + ((size_t)i << 1);
    f4v a = sp[0], b = sp[1];
    us8 o;
#pragma unroll
    for (int j = 0; j < 4; j++) { o[j] = f2bf(a[j]); o[j + 4] = f2bf(b[j]); }
    *(us8*)(d + ((size_t)i << 3)) = o;
}

// ---------- bf16 NT GEMM: C[r][n] = sum_k A[r][k]*B[n][k], bf16 out ----------
__global__ __launch_bounds__(256) void gemm_bt(const unsigned short* __restrict__ Amat,
                                               const unsigned short* __restrict__ Bmat,
                                               unsigned short* __restrict__ Cmat,
                                               int M, int N, int K, int permute) {
    const int nbn = N >> 7;
    const int bm = (blockIdx.x / nbn) << 7;
    const int bn = (blockIdx.x % nbn) << 7;
    const int tid = threadIdx.x;
    const int w = tid >> 6, l = tid & 63;
    const int wr = (w >> 1) << 6, wc = (w & 1) << 6;
    const int lo = l & 15, hi = l >> 4;

    __shared__ alignas(16) unsigned short As[128 * 32];
    __shared__ alignas(16) unsigned short Bs[128 * 32];

    f32x4 acc[4][4];
#pragma unroll
    for (int i = 0; i < 4; i++)
#pragma unroll
        for (int j = 0; j < 4; j++) acc[i][j] = (f32x4){0.f, 0.f, 0.f, 0.f};

    const int lin0 = tid, lin1 = 256 + tid;
    const int r0 = lin0 >> 2, c0 = (lin0 & 3) << 3;
    const int r1 = lin1 >> 2, c1 = (lin1 & 3) << 3;
    const size_t Kz = (size_t)K;

    us8 ra0 = *(const us8*)(Amat + (size_t)(bm + r0) * Kz + c0);
    us8 ra1 = *(const us8*)(Amat + (size_t)(bm + r1) * Kz + c1);
    us8 rb0 = *(const us8*)(Bmat + (size_t)(bn + r0) * Kz + c0);
    us8 rb1 = *(const us8*)(Bmat + (size_t)(bn + r1) * Kz + c1);

    const int NT = K >> 5;
    for (int kt = 0; kt < NT; ++kt) {
        __syncthreads();
        *(us8*)(As + r0 * 32 + c0) = ra0;
        *(us8*)(As + r1 * 32 + c1) = ra1;
        *(us8*)(Bs + r0 * 32 + c0) = rb0;
        *(us8*)(Bs + r1 * 32 + c1) = rb1;
        __syncthreads();
        if (kt + 1 < NT) {
            const int k0 = (kt + 1) << 5;
            ra0 = *(const us8*)(Amat + (size_t)(bm + r0) * Kz + k0 + c0);
            ra1 = *(const us8*)(Amat + (size_t)(bm + r1) * Kz + k0 + c1);
            rb0 = *(const us8*)(Bmat + (size_t)(bn + r0) * Kz + k0 + c0);
            rb1 = *(const us8*)(Bmat + (size_t)(bn + r1) * Kz + k0 + c1);
        }
        bf16x8 af[4], bfm[4];
#pragma unroll
        for (int mi = 0; mi < 4; ++mi)
            af[mi] = as_bf16x8(*(const us8*)(As + (wr + mi * 16 + lo) * 32 + hi * 8));
#pragma unroll
        for (int ni = 0; ni < 4; ++ni)
            bfm[ni] = as_bf16x8(*(const us8*)(Bs + (wc + ni * 16 + lo) * 32 + hi * 8));
#pragma unroll
        for (int mi = 0; mi < 4; ++mi)
#pragma unroll
            for (int ni = 0; ni < 4; ++ni)
                acc[mi][ni] = __builtin_amdgcn_mfma_f32_16x16x32_bf16(af[mi], bfm[ni], acc[mi][ni], 0, 0, 0);
    }

#pragma unroll
    for (int mi = 0; mi < 4; ++mi) {
#pragma unroll
        for (int r = 0; r < 4; ++r) {
            const int gr = bm + wr + mi * 16 + hi * 4 + r;
            const size_t orow = permute ? ((size_t)(gr & 31) * (size_t)(M >> 5) + (size_t)(gr >> 5))
                                        : (size_t)gr;
            unsigned short* crow = Cmat + orow * (size_t)N + bn + wc;
#pragma unroll
            for (int ni = 0; ni < 4; ++ni)
                crow[ni * 16 + lo] = f2bf(acc[mi][ni][r]);
        }
    }
}

// ---------- sequential scan: h = tanh(h@A^T + xb_t), persistent, 64 blocks ----------
// Exchange redesigned: all h traffic is agent-scope (sc0 sc1 -> LLC, memory-side
// coherent); L2 never dirty -> flag RELEASE wbl2 is empty; no cache invalidates
// needed. Per-block flag words replace the contended atomic counter.
// MFMA roles swapped (A-op = A panel, B-op = h): D gives each lane 4 consecutive
// d for one batch -> h'/hs/xb are single 8B ops per lane.
#define NBLK 64
__global__ __launch_bounds__(128) void scan_ker(const unsigned short* __restrict__ Abf,
                                                const unsigned short* __restrict__ xb,
                                                unsigned short* __restrict__ hs,
                                                unsigned short* __restrict__ hbuf,
                                                unsigned* __restrict__ flags) {
    const int tid = threadIdx.x;
    const int w = tid >> 6, l = tid & 63;
    const int lo = l & 15, hi = l >> 4;
    const int n0 = blockIdx.x << 4;                 // 16 output cols per block

    __shared__ alignas(16) unsigned short Apan[16 * 1024];   // swizzled A panel, 32 KB

    for (int idx = tid; idx < 2048; idx += 128) {
        const int row = idx >> 7;
        const int kb = (idx & 127) << 4;
        us8 v = *(const us8*)(Abf + (size_t)(n0 + row) * 1024 + ((idx & 127) << 3));
        *(us8*)((char*)Apan + row * 2048 + (kb ^ ((row & 7) << 4))) = v;
    }

    const int batch = (w << 4) + lo;                // B-operand row (batch), wave-split
    const int dout0 = n0 + (hi << 2);               // 4 consecutive output d per lane
    const int swb = (lo & 7) << 4;

    const u64* xbp = (const u64*)(xb + (size_t)batch * 1048576 + dout0);   // stride 256 u64/t
    u64* hsp = (u64*)hs + (((size_t)batch << 10) + dout0 >> 2);            // stride 8192 u64/t
    u64* hq0 = (u64*)hbuf;                          // two buffers of 8192 u64
    u64* hq1 = hq0 + 8192;
    const int hread_off = (batch << 8) + (hi << 1); // u64 idx; frag kk at +kk*8
    const int hwrite_off = (batch << 8) + (dout0 >> 2);
    unsigned* myflag = flags + (blockIdx.x << 5);   // 128B-strided flag words

    u64 xbq = xbp[0];
    __syncthreads();                                // A panel ready

    for (int t = 0; t < 1024; ++t) {
        const u64* hr = ((t & 1) ? hq1 : hq0) + hread_off;
        u64* hwv = ((t & 1) ? hq0 : hq1) + hwrite_off;

        f32x4 acc0 = {0.f, 0.f, 0.f, 0.f}, acc1 = {0.f, 0.f, 0.f, 0.f};
        u64 qa[8][2];
#pragma unroll
        for (int i = 0; i < 8; i++) {               // pipeline depth 8
            qa[i][0] = __hip_atomic_load(hr + i * 8,     __ATOMIC_RELAXED, __HIP_MEMORY_SCOPE_AGENT);
            qa[i][1] = __hip_atomic_load(hr + i * 8 + 1, __ATOMIC_RELAXED, __HIP_MEMORY_SCOPE_AGENT);
        }
#pragma unroll
        for (int kk = 0; kk < 32; ++kk) {
            BC8 f; f.q[0] = qa[kk & 7][0]; f.q[1] = qa[kk & 7][1];
            const int kbyte = (kk << 6) + (hi << 4);
            BC8 p; p.u = *(const us8*)((const char*)Apan + lo * 2048 + (kbyte ^ swb));
            if (kk & 1) acc1 = __builtin_amdgcn_mfma_f32_16x16x32_bf16(p.b, f.b, acc1, 0, 0, 0);
            else        acc0 = __builtin_amdgcn_mfma_f32_16x16x32_bf16(p.b, f.b, acc0, 0, 0, 0);
            if (kk < 24) {
                qa[kk & 7][0] = __hip_atomic_load(hr + (kk + 8) * 8,     __ATOMIC_RELAXED, __HIP_MEMORY_SCOPE_AGENT);
                qa[kk & 7][1] = __hip_atomic_load(hr + (kk + 8) * 8 + 1, __ATOMIC_RELAXED, __HIP_MEMORY_SCOPE_AGENT);
            }
        }
        f32x4 acc = acc0 + acc1;
        u64 xbq_next = 0;
        if (t < 1023) xbq_next = xbp[(size_t)(t + 1) << 8];

        union { us4 s; u64 q; } pk;
#pragma unroll
        for (int r = 0; r < 4; r++) {
            const float xv = bf2f((unsigned short)((xbq >> (16 * r)) & 0xFFFFu));
            float s = acc[r] + xv;
            s = fminf(fmaxf(s, -15.f), 15.f);
            const float e = __expf(2.f * s);
            const float th = 1.f - __fdividef(2.f, e + 1.f);
            pk.s[r] = f2bf(th);
        }
        __hip_atomic_store(hwv, pk.q, __ATOMIC_RELAXED, __HIP_MEMORY_SCOPE_AGENT);
        __hip_atomic_store(hsp + ((size_t)t << 13), pk.q, __ATOMIC_RELAXED, __HIP_MEMORY_SCOPE_AGENT);
        xbq = xbq_next;

        __syncthreads();                            // both waves' stores vmcnt-acked at LLC
        if (tid == 0)
            __hip_atomic_store(myflag, (unsigned)(t + 1), __ATOMIC_RELEASE, __HIP_MEMORY_SCOPE_AGENT);
        if (w == 0) {                               // wave 0 polls all 64 flags (lane l -> block l)
            while (__hip_atomic_load(flags + (l << 5), __ATOMIC_ACQUIRE, __HIP_MEMORY_SCOPE_AGENT)
                   < (unsigned)(t + 1)) {}
        }
        __syncthreads();
    }
}

// ---------- fused add-x + LayerNorm, one wave per row ----------
__global__ __launch_bounds__(256) void ln_ker(const unsigned short* __restrict__ y,
                                              const float* __restrict__ x,
                                              const float* __restrict__ gamma,
                                              const float* __restrict__ beta,
                                              float* __restrict__ out) {
    const int row = (blockIdx.x << 2) + (threadIdx.x >> 6);
    const int l = threadIdx.x & 63;
    const unsigned short* yr = y + (size_t)row * 1024;
    const float* xr = x + (size_t)row * 1024;
    float v[16];
    float s = 0.f, s2 = 0.f;
#pragma unroll
    for (int j = 0; j < 4; j++) {
        const int e = ((j << 6) + l) << 2;
        f4v xv = *(const f4v*)(xr + e);
        us4 yv = *(const us4*)(yr + e);
#pragma unroll
        for (int i = 0; i < 4; i++) {
            float t = xv[i] + bf2f(yv[i]);
            v[(j << 2) + i] = t; s += t; s2 += t * t;
        }
    }
#pragma unroll
    for (int off = 1; off < 64; off <<= 1) {
        s += __shfl_xor(s, off, 64);
        s2 += __shfl_xor(s2, off, 64);
    }
    const float mu = s * (1.f / 1024.f);
    const float var = fmaxf(s2 * (1.f / 1024.f) - mu * mu, 0.f);
    const float rs = rsqrtf(var + 1e-5f);
#pragma unroll
    for (int j = 0; j < 4; j++) {
        const int e = ((j << 6) + l) << 2;
        f4v g = *(const f4v*)(gamma + e);
        f4v bt = *(const f4v*)(beta + e);
        f4v o;
#pragma unroll
        for (int i = 0; i < 4; i++) o[i] = (v[(j << 2) + i] - mu) * rs * g[i] + bt[i];
        *(f4v*)(out + (size_t)row * 1024 + e) = o;
    }
}

// ---------- launch ----------
extern "C" void kernel_launch(void* const* d_in, const int* in_sizes, int n_in,
                              void* d_out, int out_size, void* d_ws, size_t ws_size,
                              hipStream_t stream) {
    const float* x = (const float*)d_in[0];
    const float* Amat = (const float*)d_in[1];
    const float* Bmat = (const float*)d_in[2];
    const float* Cmat = (const float*)d_in[3];
    const float* gamma = (const float*)d_in[4];
    const float* beta = (const float*)d_in[5];
    float* out = (float*)d_out;
    char* ws = (char*)d_ws;

    const size_t R1 = 0;                       // x_bf16 (phase1) -> hs (phase2/3), 64 MiB
    const size_t R2 = 67108864;                // xb (phase1/2)   -> y tmp (phase3), 64 MiB
    const size_t OA = 134217728;               // A bf16, 2 MiB
    const size_t OB = OA + 2097152;            // B bf16
    const size_t OC = OB + 2097152;            // C bf16
    const size_t OH = OC + 2097152;            // h double buffer, 128 KiB
    const size_t OBAR = OH + 131072;           // 64 flag words, 128B-strided (8 KiB)
    if (ws_size < OBAR + 8192) return;

    unsigned short* xbf = (unsigned short*)(ws + R1);
    unsigned short* hsb = (unsigned short*)(ws + R1);
    unsigned short* xbb = (unsigned short*)(ws + R2);
    unsigned short* tmp = (unsigned short*)(ws + R2);
    unsigned short* Ab = (unsigned short*)(ws + OA);
    unsigned short* Bb = (unsigned short*)(ws + OB);
    unsigned short* Cb = (unsigned short*)(ws + OC);
    unsigned short* hbuf = (unsigned short*)(ws + OH);
    unsigned* flags = (unsigned*)(ws + OBAR);

    hipMemsetAsync(ws + OH, 0, 131072 + 8192, stream);         // h0 = 0, flags = 0

    cvt_ker<<<16384, 256, 0, stream>>>(x, xbf, 4194304);       // x -> bf16
    cvt_ker<<<512, 256, 0, stream>>>(Amat, Ab, 131072);
    cvt_ker<<<512, 256, 0, stream>>>(Bmat, Bb, 131072);
    cvt_ker<<<512, 256, 0, stream>>>(Cmat, Cb, 131072);

    // xb[b][s][e] = sum_d x[b][s][d]*B[e][d]
    gemm_bt<<<2048, 256, 0, stream>>>(xbf, Bb, xbb, 32768, 1024, 1024, 0);

    // sequential recurrence; writes hs[t][b][d]
    scan_ker<<<NBLK, 128, 0, stream>>>(Ab, xbb, hsb, hbuf, flags);

    // y[t*32+b][e] = sum_d hs[..][d]*C[e][d], stored permuted as tmp[b][s][e]
    gemm_bt<<<2048, 256, 0, stream>>>(hsb, Cb, tmp, 32768, 1024, 1024, 1);

    // out = LN(y + x)
    ln_ker<<<8192, 256, 0, stream>>>(tmp, x, gamma, beta, out);
}

// Round 4
// 5768.882 us; speedup vs baseline: 1.7013x; 1.0942x over previous
//
#include <hip/hip_runtime.h>
#include <hip/hip_bf16.h>
#include <math.h>

// ---------- types ----------
typedef __attribute__((ext_vector_type(8))) __bf16 bf16x8;
typedef __attribute__((ext_vector_type(4))) float f32x4;
typedef __attribute__((ext_vector_type(4))) float f4v;
typedef __attribute__((ext_vector_type(8))) unsigned short us8;
typedef __attribute__((ext_vector_type(4))) unsigned short us4;
typedef __attribute__((ext_vector_type(4))) unsigned int u32x4;
typedef unsigned long long u64;

__device__ __forceinline__ unsigned short f2bf(float f) {
    unsigned u = __float_as_uint(f);
    unsigned r = (u + 0x7FFFu + ((u >> 16) & 1u)) >> 16;   // RNE
    return (unsigned short)r;
}
__device__ __forceinline__ float bf2f(unsigned short h) {
    return __uint_as_float(((unsigned)h) << 16);
}

union BC8 { us8 u; bf16x8 b; };
__device__ __forceinline__ bf16x8 as_bf16x8(us8 u) { BC8 c; c.u = u; return c.b; }

#define SB0 __builtin_amdgcn_sched_barrier(0)

#define REP16(M) M(0) M(1) M(2) M(3) M(4) M(5) M(6) M(7) M(8) M(9) M(10) M(11) M(12) M(13) M(14) M(15)
#define REP32(M) REP16(M) M(16) M(17) M(18) M(19) M(20) M(21) M(22) M(23) M(24) M(25) M(26) M(27) M(28) M(29) M(30) M(31)

// ---------- fp32 -> bf16 convert (8 elems/thread) ----------
__global__ __launch_bounds__(256) void cvt_ker(const float* __restrict__ s,
                                               unsigned short* __restrict__ d, int n8) {
    const int i = blockIdx.x * 256 + threadIdx.x;
    if (i >= n8) return;
    const f4v* sp = (const f4v*)s + ((size_t)i << 1);
    f4v a = sp[0], b = sp[1];
    us8 o;
#pragma unroll
    for (int j = 0; j < 4; j++) { o[j] = f2bf(a[j]); o[j + 4] = f2bf(b[j]); }
    *(us8*)(d + ((size_t)i << 3)) = o;
}

// ---------- bf16 NT GEMM: C[r][n] = sum_k A[r][k]*B[n][k], bf16 out ----------
__global__ __launch_bounds__(256) void gemm_bt(const unsigned short* __restrict__ Amat,
                                               const unsigned short* __restrict__ Bmat,
                                               unsigned short* __restrict__ Cmat,
                                               int M, int N, int K, int permute) {
    const int nbn = N >> 7;
    const int bm = (blockIdx.x / nbn) << 7;
    const int bn = (blockIdx.x % nbn) << 7;
    const int tid = threadIdx.x;
    const int w = tid >> 6, l = tid & 63;
    const int wr = (w >> 1) << 6, wc = (w & 1) << 6;
    const int lo = l & 15, hi = l >> 4;

    __shared__ alignas(16) unsigned short As[128 * 32];
    __shared__ alignas(16) unsigned short Bs[128 * 32];

    f32x4 acc[4][4];
#pragma unroll
    for (int i = 0; i < 4; i++)
#pragma unroll
        for (int j = 0; j < 4; j++) acc[i][j] = (f32x4){0.f, 0.f, 0.f, 0.f};

    const int lin0 = tid, lin1 = 256 + tid;
    const int r0 = lin0 >> 2, c0 = (lin0 & 3) << 3;
    const int r1 = lin1 >> 2, c1 = (lin1 & 3) << 3;
    const size_t Kz = (size_t)K;

    us8 ra0 = *(const us8*)(Amat + (size_t)(bm + r0) * Kz + c0);
    us8 ra1 = *(const us8*)(Amat + (size_t)(bm + r1) * Kz + c1);
    us8 rb0 = *(const us8*)(Bmat + (size_t)(bn + r0) * Kz + c0);
    us8 rb1 = *(const us8*)(Bmat + (size_t)(bn + r1) * Kz + c1);

    const int NT = K >> 5;
    for (int kt = 0; kt < NT; ++kt) {
        __syncthreads();
        *(us8*)(As + r0 * 32 + c0) = ra0;
        *(us8*)(As + r1 * 32 + c1) = ra1;
        *(us8*)(Bs + r0 * 32 + c0) = rb0;
        *(us8*)(Bs + r1 * 32 + c1) = rb1;
        __syncthreads();
        if (kt + 1 < NT) {
            const int k0 = (kt + 1) << 5;
            ra0 = *(const us8*)(Amat + (size_t)(bm + r0) * Kz + k0 + c0);
            ra1 = *(const us8*)(Amat + (size_t)(bm + r1) * Kz + k0 + c1);
            rb0 = *(const us8*)(Bmat + (size_t)(bn + r0) * Kz + k0 + c0);
            rb1 = *(const us8*)(Bmat + (size_t)(bn + r1) * Kz + k0 + c1);
        }
        bf16x8 af[4], bfm[4];
#pragma unroll
        for (int mi = 0; mi < 4; ++mi)
            af[mi] = as_bf16x8(*(const us8*)(As + (wr + mi * 16 + lo) * 32 + hi * 8));
#pragma unroll
        for (int ni = 0; ni < 4; ++ni)
            bfm[ni] = as_bf16x8(*(const us8*)(Bs + (wc + ni * 16 + lo) * 32 + hi * 8));
#pragma unroll
        for (int mi = 0; mi < 4; ++mi)
#pragma unroll
            for (int ni = 0; ni < 4; ++ni)
                acc[mi][ni] = __builtin_amdgcn_mfma_f32_16x16x32_bf16(af[mi], bfm[ni], acc[mi][ni], 0, 0, 0);
    }

#pragma unroll
    for (int mi = 0; mi < 4; ++mi) {
#pragma unroll
        for (int r = 0; r < 4; ++r) {
            const int gr = bm + wr + mi * 16 + hi * 4 + r;
            const size_t orow = permute ? ((size_t)(gr & 31) * (size_t)(M >> 5) + (size_t)(gr >> 5))
                                        : (size_t)gr;
            unsigned short* crow = Cmat + orow * (size_t)N + bn + wc;
#pragma unroll
            for (int ni = 0; ni < 4; ++ni)
                crow[ni * 16 + lo] = f2bf(acc[mi][ni][r]);
        }
    }
}

// ---------- sequential scan: h_t = tanh(h_{t-1}@A^T + xb_t) ----------
// 64 blocks x 128 threads (2 independent waves; wave W owns batches W*16..W*16+15,
// block owns output cols n0..n0+15). A-panel entirely in registers (32 x 16B per
// lane) -> no LDS, no __syncthreads. hs[t][b][d] doubles as the exchange buffer
// (slot 0 = h0 = 0). Critical-path VMEM is inline asm with hand-counted vmcnt:
// depth-16 pipeline of 16B sc0/sc1 loads (all waits resolve to vmcnt(15) while
// the pipe is full). Per-(block,wave,step) tags gate consumers; producer tags
// only after vmcnt(0) ack at the coherence point.
__global__ __launch_bounds__(128, 1) void scan_ker(const unsigned short* __restrict__ Abf,
                                                   const unsigned short* __restrict__ xb,
                                                   unsigned short* __restrict__ hs,
                                                   unsigned* __restrict__ tags) {
    const int tid = threadIdx.x;
    const int W = tid >> 6, l = tid & 63;
    const int lo = l & 15, hi = l >> 4;
    const int n0 = blockIdx.x << 4;
    const int batch = (W << 4) + lo;

    // ---- A panel -> registers: areg[kk] = A[n0+lo][kk*32 + hi*8 .. +7] ----
    u32x4 areg[32];
    u64 aaddr = (u64)(const char*)(Abf + ((size_t)(n0 + lo) << 10) + (hi << 3));
#define ALOAD(kk) asm volatile("global_load_dwordx4 %0, %1, off offset:%2" \
                               : "=&v"(areg[kk]) : "v"(aaddr), "n"((kk) * 64));
    REP32(ALOAD)
#undef ALOAD
    asm volatile("s_waitcnt vmcnt(0)" ::: "memory");
    SB0;

    // ---- per-step pointers (byte addresses) ----
    u64 hrd = (u64)(const char*)hs + ((size_t)batch << 11) + (hi << 4);            // + t*65536
    u64 hwr = (u64)(char*)hs + 65536 + ((size_t)batch << 11) + ((size_t)(n0 + (hi << 2)) << 1);
    u64 xrd = (u64)(const char*)xb + (((size_t)batch << 20) + n0 + (hi << 2)) * 2; // + 2048/step
    u64 twr = (u64)(char*)tags + ((size_t)((blockIdx.x << 1) + W) << 2);           // + 512/step
    const unsigned* prd = tags + ((l << 1) + W);                                   // + 128 words/step
    const unsigned one = 1;

    u32x4 hq[16];

    for (int t = 0; t < 1024; ++t) {
        if (t > 0) {
            while (__hip_atomic_load(prd, __ATOMIC_RELAXED, __HIP_MEMORY_SCOPE_AGENT) == 0) {}
            prd += 128;
        }
        SB0;
        u64 xq;
        asm volatile("global_load_dwordx2 %0, %1, off" : "=&v"(xq) : "v"(xrd));
#define HLOAD0(kk) asm volatile("global_load_dwordx4 %0, %1, off offset:%2 sc0 sc1" \
                                : "=&v"(hq[kk]) : "v"(hrd), "n"((kk) * 64));
        REP16(HLOAD0)
#undef HLOAD0
        f32x4 acc0 = {0.f, 0.f, 0.f, 0.f}, acc1 = {0.f, 0.f, 0.f, 0.f};
#define STEP(kk) { \
        asm volatile("s_waitcnt vmcnt(%0)" :: "n"((kk) < 16 ? 15 : (31 - (kk))) : "memory"); \
        SB0; \
        bf16x8 a_ = __builtin_bit_cast(bf16x8, areg[kk]); \
        bf16x8 h_ = __builtin_bit_cast(bf16x8, hq[(kk) & 15]); \
        if ((kk) & 1) acc1 = __builtin_amdgcn_mfma_f32_16x16x32_bf16(a_, h_, acc1, 0, 0, 0); \
        else          acc0 = __builtin_amdgcn_mfma_f32_16x16x32_bf16(a_, h_, acc0, 0, 0, 0); \
        if ((kk) < 16) { \
            asm volatile("global_load_dwordx4 %0, %1, off offset:%2 sc0 sc1" \
                         : "=&v"(hq[(kk) & 15]) : "v"(hrd), "n"((((kk) & 15) + 16) * 64)); \
        } }
        REP32(STEP)
#undef STEP
        SB0;
        f32x4 z = acc0 + acc1;
        union { us4 h; u64 q; } pk;
#pragma unroll
        for (int r = 0; r < 4; r++) {
            const float xv = bf2f((unsigned short)((xq >> (16 * r)) & 0xFFFFu));
            float s = z[r] + xv;
            s = fminf(fmaxf(s, -15.f), 15.f);
            const float e = __expf(2.f * s);
            pk.h[r] = f2bf(1.f - __fdividef(2.f, e + 1.f));
        }
        asm volatile("global_store_dwordx2 %0, %1, off sc0 sc1" :: "v"(hwr), "v"(pk.q) : "memory");
        asm volatile("s_waitcnt vmcnt(0)" ::: "memory");          // data at coherence point
        SB0;
        if (l == 0)
            asm volatile("global_store_dword %0, %1, off sc0 sc1" :: "v"(twr), "v"(one) : "memory");
        hrd += 65536; hwr += 65536; xrd += 2048; twr += 512;
    }
}

// ---------- fused add-x + LayerNorm, one wave per row ----------
__global__ __launch_bounds__(256) void ln_ker(const unsigned short* __restrict__ y,
                                              const float* __restrict__ x,
                                              const float* __restrict__ gamma,
                                              const float* __restrict__ beta,
                                              float* __restrict__ out) {
    const int row = (blockIdx.x << 2) + (threadIdx.x >> 6);
    const int l = threadIdx.x & 63;
    const unsigned short* yr = y + (size_t)row * 1024;
    const float* xr = x + (size_t)row * 1024;
    float v[16];
    float s = 0.f, s2 = 0.f;
#pragma unroll
    for (int j = 0; j < 4; j++) {
        const int e = ((j << 6) + l) << 2;
        f4v xv = *(const f4v*)(xr + e);
        us4 yv = *(const us4*)(yr + e);
#pragma unroll
        for (int i = 0; i < 4; i++) {
            float t = xv[i] + bf2f(yv[i]);
            v[(j << 2) + i] = t; s += t; s2 += t * t;
        }
    }
#pragma unroll
    for (int off = 1; off < 64; off <<= 1) {
        s += __shfl_xor(s, off, 64);
        s2 += __shfl_xor(s2, off, 64);
    }
    const float mu = s * (1.f / 1024.f);
    const float var = fmaxf(s2 * (1.f / 1024.f) - mu * mu, 0.f);
    const float rs = rsqrtf(var + 1e-5f);
#pragma unroll
    for (int j = 0; j < 4; j++) {
        const int e = ((j << 6) + l) << 2;
        f4v g = *(const f4v*)(gamma + e);
        f4v bt = *(const f4v*)(beta + e);
        f4v o;
#pragma unroll
        for (int i = 0; i < 4; i++) o[i] = (v[(j << 2) + i] - mu) * rs * g[i] + bt[i];
        *(f4v*)(out + (size_t)row * 1024 + e) = o;
    }
}

// ---------- launch ----------
extern "C" void kernel_launch(void* const* d_in, const int* in_sizes, int n_in,
                              void* d_out, int out_size, void* d_ws, size_t ws_size,
                              hipStream_t stream) {
    const float* x = (const float*)d_in[0];
    const float* Amat = (const float*)d_in[1];
    const float* Bmat = (const float*)d_in[2];
    const float* Cmat = (const float*)d_in[3];
    const float* gamma = (const float*)d_in[4];
    const float* beta = (const float*)d_in[5];
    float* out = (float*)d_out;
    char* ws = (char*)d_ws;

    // layout (bytes):
    //   R1 = 0          : hs[1025][32][1024] bf16 (67,174,400) ; first 64MiB = xbf in phase 1
    //   R2 = 67,174,400 : xb (phase 1/2) -> y tmp (phase 3), 64 MiB
    //   OA              : A bf16 (2 MiB)
    //   OB              : B bf16 (2 MiB); first 512 KiB reused as tags after GEMM1
    //   OC              : C bf16 (2 MiB)
    const size_t R1 = 0;
    const size_t R2 = 67174400;
    const size_t OA = R2 + 67108864;
    const size_t OB = OA + 2097152;
    const size_t OC = OB + 2097152;
    const size_t END = OC + 2097152;
    if (ws_size < END) return;

    unsigned short* hsb = (unsigned short*)(ws + R1);       // hs base (slot 0 = h0)
    unsigned short* xbf = (unsigned short*)(ws + R1);       // x bf16 (phase 1 alias)
    unsigned short* xbb = (unsigned short*)(ws + R2);
    unsigned short* tmp = (unsigned short*)(ws + R2);
    unsigned short* Ab = (unsigned short*)(ws + OA);
    unsigned short* Bb = (unsigned short*)(ws + OB);
    unsigned short* Cb = (unsigned short*)(ws + OC);
    unsigned* tags = (unsigned*)(ws + OB);                  // alias over dead B bf16

    cvt_ker<<<16384, 256, 0, stream>>>(x, xbf, 4194304);    // x -> bf16
    cvt_ker<<<512, 256, 0, stream>>>(Amat, Ab, 131072);
    cvt_ker<<<512, 256, 0, stream>>>(Bmat, Bb, 131072);
    cvt_ker<<<512, 256, 0, stream>>>(Cmat, Cb, 131072);

    // xb[b][s][e] = sum_d x[b][s][d]*B[e][d]
    gemm_bt<<<2048, 256, 0, stream>>>(xbf, Bb, xbb, 32768, 1024, 1024, 0);

    // zero h0 slot (overwrites dead xbf head) and tags (overwrites dead B bf16)
    hipMemsetAsync(ws + R1, 0, 65536, stream);
    hipMemsetAsync(ws + OB, 0, 524288, stream);

    // sequential recurrence; writes hs[t+1][b][d]
    scan_ker<<<64, 128, 0, stream>>>(Ab, xbb, hsb, tags);

    // y rows (t*32+b) <- hs[t+1][b][:], output permuted to tmp[b][t][e]
    gemm_bt<<<2048, 256, 0, stream>>>(hsb + 32768, Cb, tmp, 32768, 1024, 1024, 1);

    // out = LN(y + x)
    ln_ker<<<8192, 256, 0, stream>>>(tmp, x, gamma, beta, out);
}

// Round 7
// 5696.136 us; speedup vs baseline: 1.7230x; 1.0128x over previous
//
#include <hip/hip_runtime.h>
#include <hip/hip_bf16.h>
#include <math.h>

// ---------- types ----------
typedef __attribute__((ext_vector_type(8))) __bf16 bf16x8;
typedef __attribute__((ext_vector_type(4))) float f32x4;
typedef __attribute__((ext_vector_type(4))) float f4v;
typedef __attribute__((ext_vector_type(8))) unsigned short us8;
typedef __attribute__((ext_vector_type(4))) unsigned short us4;
typedef __attribute__((ext_vector_type(4))) unsigned int u32x4;
typedef unsigned long long u64;

__device__ __forceinline__ unsigned short f2bf(float f) {
    unsigned u = __float_as_uint(f);
    unsigned r = (u + 0x7FFFu + ((u >> 16) & 1u)) >> 16;   // RNE
    return (unsigned short)r;
}
__device__ __forceinline__ float bf2f(unsigned short h) {
    return __uint_as_float(((unsigned)h) << 16);
}

union BC8 { us8 u; bf16x8 b; };
__device__ __forceinline__ bf16x8 as_bf16x8(us8 u) { BC8 c; c.u = u; return c.b; }

#define SB0 __builtin_amdgcn_sched_barrier(0)

#define REP16(M) M(0) M(1) M(2) M(3) M(4) M(5) M(6) M(7) M(8) M(9) M(10) M(11) M(12) M(13) M(14) M(15)
#define REP32(M) REP16(M) M(16) M(17) M(18) M(19) M(20) M(21) M(22) M(23) M(24) M(25) M(26) M(27) M(28) M(29) M(30) M(31)

// ---------- fp32 -> bf16 convert (8 elems/thread) ----------
__global__ __launch_bounds__(256) void cvt_ker(const float* __restrict__ s,
                                               unsigned short* __restrict__ d, int n8) {
    const int i = blockIdx.x * 256 + threadIdx.x;
    if (i >= n8) return;
    const f4v* sp = (const f4v*)s + ((size_t)i << 1);
    f4v a = sp[0], b = sp[1];
    us8 o;
#pragma unroll
    for (int j = 0; j < 4; j++) { o[j] = f2bf(a[j]); o[j + 4] = f2bf(b[j]); }
    *(us8*)(d + ((size_t)i << 3)) = o;
}

// ---------- bf16 NT GEMM: C[r][n] = sum_k A[r][k]*B[n][k], bf16 out ----------
__global__ __launch_bounds__(256) void gemm_bt(const unsigned short* __restrict__ Amat,
                                               const unsigned short* __restrict__ Bmat,
                                               unsigned short* __restrict__ Cmat,
                                               int M, int N, int K, int permute) {
    const int nbn = N >> 7;
    const int bm = (blockIdx.x / nbn) << 7;
    const int bn = (blockIdx.x % nbn) << 7;
    const int tid = threadIdx.x;
    const int w = tid >> 6, l = tid & 63;
    const int wr = (w >> 1) << 6, wc = (w & 1) << 6;
    const int lo = l & 15, hi = l >> 4;

    __shared__ alignas(16) unsigned short As[128 * 32];
    __shared__ alignas(16) unsigned short Bs[128 * 32];

    f32x4 acc[4][4];
#pragma unroll
    for (int i = 0; i < 4; i++)
#pragma unroll
        for (int j = 0; j < 4; j++) acc[i][j] = (f32x4){0.f, 0.f, 0.f, 0.f};

    const int lin0 = tid, lin1 = 256 + tid;
    const int r0 = lin0 >> 2, c0 = (lin0 & 3) << 3;
    const int r1 = lin1 >> 2, c1 = (lin1 & 3) << 3;
    const size_t Kz = (size_t)K;

    us8 ra0 = *(const us8*)(Amat + (size_t)(bm + r0) * Kz + c0);
    us8 ra1 = *(const us8*)(Amat + (size_t)(bm + r1) * Kz + c1);
    us8 rb0 = *(const us8*)(Bmat + (size_t)(bn + r0) * Kz + c0);
    us8 rb1 = *(const us8*)(Bmat + (size_t)(bn + r1) * Kz + c1);

    const int NT = K >> 5;
    for (int kt = 0; kt < NT; ++kt) {
        __syncthreads();
        *(us8*)(As + r0 * 32 + c0) = ra0;
        *(us8*)(As + r1 * 32 + c1) = ra1;
        *(us8*)(Bs + r0 * 32 + c0) = rb0;
        *(us8*)(Bs + r1 * 32 + c1) = rb1;
        __syncthreads();
        if (kt + 1 < NT) {
            const int k0 = (kt + 1) << 5;
            ra0 = *(const us8*)(Amat + (size_t)(bm + r0) * Kz + k0 + c0);
            ra1 = *(const us8*)(Amat + (size_t)(bm + r1) * Kz + k0 + c1);
            rb0 = *(const us8*)(Bmat + (size_t)(bn + r0) * Kz + k0 + c0);
            rb1 = *(const us8*)(Bmat + (size_t)(bn + r1) * Kz + k0 + c1);
        }
        bf16x8 af[4], bfm[4];
#pragma unroll
        for (int mi = 0; mi < 4; ++mi)
            af[mi] = as_bf16x8(*(const us8*)(As + (wr + mi * 16 + lo) * 32 + hi * 8));
#pragma unroll
        for (int ni = 0; ni < 4; ++ni)
            bfm[ni] = as_bf16x8(*(const us8*)(Bs + (wc + ni * 16 + lo) * 32 + hi * 8));
#pragma unroll
        for (int mi = 0; mi < 4; ++mi)
#pragma unroll
            for (int ni = 0; ni < 4; ++ni)
                acc[mi][ni] = __builtin_amdgcn_mfma_f32_16x16x32_bf16(af[mi], bfm[ni], acc[mi][ni], 0, 0, 0);
    }

#pragma unroll
    for (int mi = 0; mi < 4; ++mi) {
#pragma unroll
        for (int r = 0; r < 4; ++r) {
            const int gr = bm + wr + mi * 16 + hi * 4 + r;
            const size_t orow = permute ? ((size_t)(gr & 31) * (size_t)(M >> 5) + (size_t)(gr >> 5))
                                        : (size_t)gr;
            unsigned short* crow = Cmat + orow * (size_t)N + bn + wc;
#pragma unroll
            for (int ni = 0; ni < 4; ++ni)
                crow[ni * 16 + lo] = f2bf(acc[mi][ni][r]);
        }
    }
}

// ---------- sequential scan: h_t = tanh(h_{t-1}@A^T + xb_t) ----------
// R4's PROVEN release/acquire protocol: producer stores h' (sc0 sc1), waits
// vmcnt(0) (data at coherence point), then sets its tag; consumer polls tags,
// then loads h. Changes vs R4 (all protocol-preserving):
//   * tags packed as BYTES: one step's 128 producer tags = 128 B (2 lines),
//     so a poll round is ONE coalesced load instead of a 64-line gather.
//   * own-block exemption: lane l==bid skips its own tag (own data already
//     ack'd), removing a guaranteed-failed first poll round.
//   * xb prefetched one step ahead; it occupies the same slot in the vmcnt
//     formula that xq did in R4 (t=1023: one fewer op -> waits remain correct).
// 64 blocks x 128 threads; 2 independent waves (wave W owns batches W*16+..);
// A panel in registers; no LDS, no __syncthreads.
__global__ __launch_bounds__(128, 1) void scan_ker(const unsigned short* __restrict__ Abf,
                                                   const unsigned short* __restrict__ xb,
                                                   unsigned short* __restrict__ hs,
                                                   unsigned char* __restrict__ tags) {
    const int tid = threadIdx.x;
    const int W = tid >> 6, l = tid & 63;
    const int lo = l & 15, hi = l >> 4;
    const int n0 = blockIdx.x << 4;
    const int batch = (W << 4) + lo;
    const int bid = blockIdx.x;

    // ---- A panel -> registers: areg[kk] = A[n0+lo][kk*32 + hi*8 .. +7] ----
    u32x4 areg[32];
    u64 aaddr = (u64)(const char*)(Abf + ((size_t)(n0 + lo) << 10) + (hi << 3));
#define ALOAD(kk) asm volatile("global_load_dwordx4 %0, %1, off offset:%2" \
                               : "=&v"(areg[kk]) : "v"(aaddr), "n"((kk) * 64));
    REP32(ALOAD)
#undef ALOAD

    // ---- per-step pointers (byte addresses) ----
    u64 hrd = (u64)(const char*)hs + ((size_t)batch << 11) + (hi << 4);            // slot t; +65536/step
    u64 hwr = (u64)(char*)hs + 65536 + ((size_t)batch << 11) + ((size_t)(n0 + (hi << 2)) << 1);
    u64 xrd = (u64)(const char*)xb + (((size_t)batch << 20) + n0 + (hi << 2)) * 2; // +2048/step
    u64 trd = (u64)(const char*)tags + 128 + (l << 1) + W;                         // poll byte, row 1
    u64 twr = (u64)(char*)tags + 128 + (bid << 1) + W;                             // own byte, row 1
    const unsigned one = 1;

    u64 xq;
    asm volatile("global_load_dwordx2 %0, %1, off" : "=&v"(xq) : "v"(xrd));        // xb for t=0
    asm volatile("s_waitcnt vmcnt(0)" ::: "memory");
    SB0;

    u32x4 hq[16];

    for (int t = 0; t < 1024; ++t) {
        if (t > 0) {
            // poll packed tag row t; every round drains vmcnt (also retires the
            // un-ack'd tag store from the previous step's tail)
            while (1) {
                unsigned pb;
                asm volatile("global_load_ubyte %0, %1, off sc0 sc1"
                             : "=&v"(pb) : "v"(trd));
                asm volatile("s_waitcnt vmcnt(0)" ::: "memory");
                SB0;
                if (__all((int)((pb != 0u) | (l == bid)))) break;
            }
            trd += 128;
        }
        SB0;
        xrd += 2048;
        u64 xqn = 0;
        if (t < 1023)
            asm volatile("global_load_dwordx2 %0, %1, off" : "=&v"(xqn) : "v"(xrd));
#define HLOAD0(kk) asm volatile("global_load_dwordx4 %0, %1, off offset:%2 sc0 sc1" \
                                : "=&v"(hq[kk]) : "v"(hrd), "n"((kk) * 64));
        REP16(HLOAD0)
#undef HLOAD0
        f32x4 acc0 = {0.f, 0.f, 0.f, 0.f}, acc1 = {0.f, 0.f, 0.f, 0.f};
#define STEP(kk) { \
        asm volatile("s_waitcnt vmcnt(%0)" :: "n"((kk) < 16 ? 15 : (31 - (kk))) : "memory"); \
        SB0; \
        bf16x8 a_ = __builtin_bit_cast(bf16x8, areg[kk]); \
        bf16x8 h_ = __builtin_bit_cast(bf16x8, hq[(kk) & 15]); \
        if ((kk) & 1) acc1 = __builtin_amdgcn_mfma_f32_16x16x32_bf16(a_, h_, acc1, 0, 0, 0); \
        else          acc0 = __builtin_amdgcn_mfma_f32_16x16x32_bf16(a_, h_, acc0, 0, 0, 0); \
        if ((kk) < 16) { \
            asm volatile("global_load_dwordx4 %0, %1, off offset:%2 sc0 sc1" \
                         : "=&v"(hq[(kk) & 15]) : "v"(hrd), "n"((((kk) & 15) + 16) * 64)); \
        } }
        REP32(STEP)
#undef STEP
        SB0;
        f32x4 z = acc0 + acc1;
        union { us4 h; u64 q; } pk;
#pragma unroll
        for (int r = 0; r < 4; r++) {
            const float xv = bf2f((unsigned short)((xq >> (16 * r)) & 0xFFFFu));
            float s = z[r] + xv;
            s = fminf(fmaxf(s, -15.f), 15.f);
            const float e = __expf(2.f * s);
            pk.h[r] = f2bf(1.f - __fdividef(2.f, e + 1.f));
        }
        asm volatile("global_store_dwordx2 %0, %1, off sc0 sc1" :: "v"(hwr), "v"(pk.q) : "memory");
        asm volatile("s_waitcnt vmcnt(0)" ::: "memory");          // data at coherence point
        SB0;
        if (t < 1023) {
            if (l == 0)
                asm volatile("global_store_byte %0, %1, off sc0 sc1"
                             :: "v"(twr), "v"(one) : "memory");   // release tag (row t+1)
            twr += 128;
        }
        hrd += 65536; hwr += 65536;
        xq = xqn;
    }
}

// ---------- fused add-x + LayerNorm, one wave per row ----------
__global__ __launch_bounds__(256) void ln_ker(const unsigned short* __restrict__ y,
                                              const float* __restrict__ x,
                                              const float* __restrict__ gamma,
                                              const float* __restrict__ beta,
                                              float* __restrict__ out) {
    const int row = (blockIdx.x << 2) + (threadIdx.x >> 6);
    const int l = threadIdx.x & 63;
    const unsigned short* yr = y + (size_t)row * 1024;
    const float* xr = x + (size_t)row * 1024;
    float v[16];
    float s = 0.f, s2 = 0.f;
#pragma unroll
    for (int j = 0; j < 4; j++) {
        const int e = ((j << 6) + l) << 2;
        f4v xv = *(const f4v*)(xr + e);
        us4 yv = *(const us4*)(yr + e);
#pragma unroll
        for (int i = 0; i < 4; i++) {
            float t = xv[i] + bf2f(yv[i]);
            v[(j << 2) + i] = t; s += t; s2 += t * t;
        }
    }
#pragma unroll
    for (int off = 1; off < 64; off <<= 1) {
        s += __shfl_xor(s, off, 64);
        s2 += __shfl_xor(s2, off, 64);
    }
    const float mu = s * (1.f / 1024.f);
    const float var = fmaxf(s2 * (1.f / 1024.f) - mu * mu, 0.f);
    const float rs = rsqrtf(var + 1e-5f);
#pragma unroll
    for (int j = 0; j < 4; j++) {
        const int e = ((j << 6) + l) << 2;
        f4v g = *(const f4v*)(gamma + e);
        f4v bt = *(const f4v*)(beta + e);
        f4v o;
#pragma unroll
        for (int i = 0; i < 4; i++) o[i] = (v[(j << 2) + i] - mu) * rs * g[i] + bt[i];
        *(f4v*)(out + (size_t)row * 1024 + e) = o;
    }
}

// ---------- launch ----------
extern "C" void kernel_launch(void* const* d_in, const int* in_sizes, int n_in,
                              void* d_out, int out_size, void* d_ws, size_t ws_size,
                              hipStream_t stream) {
    const float* x = (const float*)d_in[0];
    const float* Amat = (const float*)d_in[1];
    const float* Bmat = (const float*)d_in[2];
    const float* Cmat = (const float*)d_in[3];
    const float* gamma = (const float*)d_in[4];
    const float* beta = (const float*)d_in[5];
    float* out = (float*)d_out;
    char* ws = (char*)d_ws;

    // layout (bytes):
    //   R1 = 0          : hs[1025][32][1024] bf16 (67,174,400) ; first 64MiB = xbf in phase 1
    //   R2 = 67,174,400 : xb (phase 1/2) -> y tmp (phase 3), 64 MiB
    //   OA              : A bf16 (2 MiB)
    //   OB              : B bf16 (2 MiB); first 128 KiB reused as packed byte tags after GEMM1
    //   OC              : C bf16 (2 MiB)
    const size_t R1 = 0;
    const size_t R2 = 67174400;
    const size_t OA = R2 + 67108864;
    const size_t OB = OA + 2097152;
    const size_t OC = OB + 2097152;
    const size_t END = OC + 2097152;
    if (ws_size < END) return;

    unsigned short* hsb = (unsigned short*)(ws + R1);       // hs base (slot 0 = h0)
    unsigned short* xbf = (unsigned short*)(ws + R1);       // x bf16 (phase 1 alias)
    unsigned short* xbb = (unsigned short*)(ws + R2);
    unsigned short* tmp = (unsigned short*)(ws + R2);
    unsigned short* Ab = (unsigned short*)(ws + OA);
    unsigned short* Bb = (unsigned short*)(ws + OB);
    unsigned short* Cb = (unsigned short*)(ws + OC);
    unsigned char* tags = (unsigned char*)(ws + OB);        // alias over dead B bf16

    cvt_ker<<<16384, 256, 0, stream>>>(x, xbf, 4194304);    // x -> bf16
    cvt_ker<<<512, 256, 0, stream>>>(Amat, Ab, 131072);
    cvt_ker<<<512, 256, 0, stream>>>(Bmat, Bb, 131072);
    cvt_ker<<<512, 256, 0, stream>>>(Cmat, Cb, 131072);

    // xb[b][s][e] = sum_d x[b][s][d]*B[e][d]
    gemm_bt<<<2048, 256, 0, stream>>>(xbf, Bb, xbb, 32768, 1024, 1024, 0);

    // zero h0 slot and packed tags (rows 0..1023, 128 B each)
    hipMemsetAsync(ws + R1, 0, 65536, stream);
    hipMemsetAsync(ws + OB, 0, 131072, stream);

    // sequential recurrence; writes hs[t+1][b][d]
    scan_ker<<<64, 128, 0, stream>>>(Ab, xbb, hsb, tags);

    // y rows (t*32+b) <- hs[t+1][b][:], output permuted to tmp[b][t][e]
    gemm_bt<<<2048, 256, 0, stream>>>(hsb + 32768, Cb, tmp, 32768, 1024, 1024, 1);

    // out = LN(y + x)
    ln_ker<<<8192, 256, 0, stream>>>(tmp, x, gamma, beta, out);
}

// Round 8
// 5686.364 us; speedup vs baseline: 1.7260x; 1.0017x over previous
//
#include <hip/hip_runtime.h>
#include <hip/hip_bf16.h>
#include <math.h>

// ---------- types ----------
typedef __attribute__((ext_vector_type(8))) __bf16 bf16x8;
typedef __attribute__((ext_vector_type(4))) float f32x4;
typedef __attribute__((ext_vector_type(4))) float f4v;
typedef __attribute__((ext_vector_type(8))) unsigned short us8;
typedef __attribute__((ext_vector_type(4))) unsigned short us4;
typedef __attribute__((ext_vector_type(4))) unsigned int u32x4;
typedef unsigned long long u64;

__device__ __forceinline__ unsigned short f2bf(float f) {
    unsigned u = __float_as_uint(f);
    unsigned r = (u + 0x7FFFu + ((u >> 16) & 1u)) >> 16;   // RNE
    return (unsigned short)r;
}
__device__ __forceinline__ float bf2f(unsigned short h) {
    return __uint_as_float(((unsigned)h) << 16);
}

union BC8 { us8 u; bf16x8 b; };
__device__ __forceinline__ bf16x8 as_bf16x8(us8 u) { BC8 c; c.u = u; return c.b; }

#define SB0 __builtin_amdgcn_sched_barrier(0)

#define REP16(M) M(0) M(1) M(2) M(3) M(4) M(5) M(6) M(7) M(8) M(9) M(10) M(11) M(12) M(13) M(14) M(15)
#define REP32(M) REP16(M) M(16) M(17) M(18) M(19) M(20) M(21) M(22) M(23) M(24) M(25) M(26) M(27) M(28) M(29) M(30) M(31)

// ---------- fp32 -> bf16 convert (8 elems/thread) ----------
__global__ __launch_bounds__(256) void cvt_ker(const float* __restrict__ s,
                                               unsigned short* __restrict__ d, int n8) {
    const int i = blockIdx.x * 256 + threadIdx.x;
    if (i >= n8) return;
    const f4v* sp = (const f4v*)s + ((size_t)i << 1);
    f4v a = sp[0], b = sp[1];
    us8 o;
#pragma unroll
    for (int j = 0; j < 4; j++) { o[j] = f2bf(a[j]); o[j + 4] = f2bf(b[j]); }
    *(us8*)(d + ((size_t)i << 3)) = o;
}

// ---------- bf16 NT GEMM: C[r][n] = sum_k A[r][k]*B[n][k], bf16 out ----------
__global__ __launch_bounds__(256) void gemm_bt(const unsigned short* __restrict__ Amat,
                                               const unsigned short* __restrict__ Bmat,
                                               unsigned short* __restrict__ Cmat,
                                               int M, int N, int K, int permute) {
    const int nbn = N >> 7;
    const int bm = (blockIdx.x / nbn) << 7;
    const int bn = (blockIdx.x % nbn) << 7;
    const int tid = threadIdx.x;
    const int w = tid >> 6, l = tid & 63;
    const int wr = (w >> 1) << 6, wc = (w & 1) << 6;
    const int lo = l & 15, hi = l >> 4;

    __shared__ alignas(16) unsigned short As[128 * 32];
    __shared__ alignas(16) unsigned short Bs[128 * 32];

    f32x4 acc[4][4];
#pragma unroll
    for (int i = 0; i < 4; i++)
#pragma unroll
        for (int j = 0; j < 4; j++) acc[i][j] = (f32x4){0.f, 0.f, 0.f, 0.f};

    const int lin0 = tid, lin1 = 256 + tid;
    const int r0 = lin0 >> 2, c0 = (lin0 & 3) << 3;
    const int r1 = lin1 >> 2, c1 = (lin1 & 3) << 3;
    const size_t Kz = (size_t)K;

    us8 ra0 = *(const us8*)(Amat + (size_t)(bm + r0) * Kz + c0);
    us8 ra1 = *(const us8*)(Amat + (size_t)(bm + r1) * Kz + c1);
    us8 rb0 = *(const us8*)(Bmat + (size_t)(bn + r0) * Kz + c0);
    us8 rb1 = *(const us8*)(Bmat + (size_t)(bn + r1) * Kz + c1);

    const int NT = K >> 5;
    for (int kt = 0; kt < NT; ++kt) {
        __syncthreads();
        *(us8*)(As + r0 * 32 + c0) = ra0;
        *(us8*)(As + r1 * 32 + c1) = ra1;
        *(us8*)(Bs + r0 * 32 + c0) = rb0;
        *(us8*)(Bs + r1 * 32 + c1) = rb1;
        __syncthreads();
        if (kt + 1 < NT) {
            const int k0 = (kt + 1) << 5;
            ra0 = *(const us8*)(Amat + (size_t)(bm + r0) * Kz + k0 + c0);
            ra1 = *(const us8*)(Amat + (size_t)(bm + r1) * Kz + k0 + c1);
            rb0 = *(const us8*)(Bmat + (size_t)(bn + r0) * Kz + k0 + c0);
            rb1 = *(const us8*)(Bmat + (size_t)(bn + r1) * Kz + k0 + c1);
        }
        bf16x8 af[4], bfm[4];
#pragma unroll
        for (int mi = 0; mi < 4; ++mi)
            af[mi] = as_bf16x8(*(const us8*)(As + (wr + mi * 16 + lo) * 32 + hi * 8));
#pragma unroll
        for (int ni = 0; ni < 4; ++ni)
            bfm[ni] = as_bf16x8(*(const us8*)(Bs + (wc + ni * 16 + lo) * 32 + hi * 8));
#pragma unroll
        for (int mi = 0; mi < 4; ++mi)
#pragma unroll
            for (int ni = 0; ni < 4; ++ni)
                acc[mi][ni] = __builtin_amdgcn_mfma_f32_16x16x32_bf16(af[mi], bfm[ni], acc[mi][ni], 0, 0, 0);
    }

#pragma unroll
    for (int mi = 0; mi < 4; ++mi) {
#pragma unroll
        for (int r = 0; r < 4; ++r) {
            const int gr = bm + wr + mi * 16 + hi * 4 + r;
            const size_t orow = permute ? ((size_t)(gr & 31) * (size_t)(M >> 5) + (size_t)(gr >> 5))
                                        : (size_t)gr;
            unsigned short* crow = Cmat + orow * (size_t)N + bn + wc;
#pragma unroll
            for (int ni = 0; ni < 4; ++ni)
                crow[ni * 16 + lo] = f2bf(acc[mi][ni][r]);
        }
    }
}

// ---------- sequential scan: h_t = tanh(h_{t-1}@A^T + xb_t) ----------
// R4/R7-proven release/acquire protocol. Single change vs R7: consumer h-data
// loads are PLAIN CACHED (no sc0/sc1). Correctness: slot t is first-touched
// by any agent only AFTER tag t is observed (tags released only after the
// producer's write-through stores are ack'd at the LLC), so no cache can hold
// a stale slot-t line within a dispatch; across graph replays the dispatch-
// boundary implicit acquire invalidates caches (same mechanism the GEMM1->scan
// xb handoff already relies on). Tags stay sc0/sc1 (cached spin would never
// observe the update); producer data stores stay write-through sc0/sc1 + ack.
// Why: R7's LLC-direct loads re-read every h line 64x at the LLC (~65k line
// transactions/step) -> fabric congestion inflated every RTT. Cached loads let
// each XCD L2 absorb its 8 blocks' re-reads (8x fewer LLC transactions).
__global__ __launch_bounds__(128, 1) void scan_ker(const unsigned short* __restrict__ Abf,
                                                   const unsigned short* __restrict__ xb,
                                                   unsigned short* __restrict__ hs,
                                                   unsigned char* __restrict__ tags) {
    const int tid = threadIdx.x;
    const int W = tid >> 6, l = tid & 63;
    const int lo = l & 15, hi = l >> 4;
    const int n0 = blockIdx.x << 4;
    const int batch = (W << 4) + lo;
    const int bid = blockIdx.x;

    // ---- A panel -> registers: areg[kk] = A[n0+lo][kk*32 + hi*8 .. +7] ----
    u32x4 areg[32];
    u64 aaddr = (u64)(const char*)(Abf + ((size_t)(n0 + lo) << 10) + (hi << 3));
#define ALOAD(kk) asm volatile("global_load_dwordx4 %0, %1, off offset:%2" \
                               : "=&v"(areg[kk]) : "v"(aaddr), "n"((kk) * 64));
    REP32(ALOAD)
#undef ALOAD

    // ---- per-step pointers (byte addresses) ----
    u64 hrd = (u64)(const char*)hs + ((size_t)batch << 11) + (hi << 4);            // slot t; +65536/step
    u64 hwr = (u64)(char*)hs + 65536 + ((size_t)batch << 11) + ((size_t)(n0 + (hi << 2)) << 1);
    u64 xrd = (u64)(const char*)xb + (((size_t)batch << 20) + n0 + (hi << 2)) * 2; // +2048/step
    u64 trd = (u64)(const char*)tags + 128 + (l << 1) + W;                         // poll byte, row 1
    u64 twr = (u64)(char*)tags + 128 + (bid << 1) + W;                             // own byte, row 1
    const unsigned one = 1;

    u64 xq;
    asm volatile("global_load_dwordx2 %0, %1, off" : "=&v"(xq) : "v"(xrd));        // xb for t=0
    asm volatile("s_waitcnt vmcnt(0)" ::: "memory");
    SB0;

    u32x4 hq[16];

    for (int t = 0; t < 1024; ++t) {
        if (t > 0) {
            // poll packed tag row t; every round drains vmcnt (also retires the
            // un-ack'd tag store from the previous step's tail)
            while (1) {
                unsigned pb;
                asm volatile("global_load_ubyte %0, %1, off sc0 sc1"
                             : "=&v"(pb) : "v"(trd));
                asm volatile("s_waitcnt vmcnt(0)" ::: "memory");
                SB0;
                if (__all((int)((pb != 0u) | (l == bid)))) break;
            }
            trd += 128;
        }
        SB0;
        xrd += 2048;
        u64 xqn = 0;
        if (t < 1023)
            asm volatile("global_load_dwordx2 %0, %1, off" : "=&v"(xqn) : "v"(xrd));
#define HLOAD0(kk) asm volatile("global_load_dwordx4 %0, %1, off offset:%2" \
                                : "=&v"(hq[kk]) : "v"(hrd), "n"((kk) * 64));
        REP16(HLOAD0)
#undef HLOAD0
        f32x4 acc0 = {0.f, 0.f, 0.f, 0.f}, acc1 = {0.f, 0.f, 0.f, 0.f};
#define STEP(kk) { \
        asm volatile("s_waitcnt vmcnt(%0)" :: "n"((kk) < 16 ? 15 : (31 - (kk))) : "memory"); \
        SB0; \
        bf16x8 a_ = __builtin_bit_cast(bf16x8, areg[kk]); \
        bf16x8 h_ = __builtin_bit_cast(bf16x8, hq[(kk) & 15]); \
        if ((kk) & 1) acc1 = __builtin_amdgcn_mfma_f32_16x16x32_bf16(a_, h_, acc1, 0, 0, 0); \
        else          acc0 = __builtin_amdgcn_mfma_f32_16x16x32_bf16(a_, h_, acc0, 0, 0, 0); \
        if ((kk) < 16) { \
            asm volatile("global_load_dwordx4 %0, %1, off offset:%2" \
                         : "=&v"(hq[(kk) & 15]) : "v"(hrd), "n"((((kk) & 15) + 16) * 64)); \
        } }
        REP32(STEP)
#undef STEP
        SB0;
        f32x4 z = acc0 + acc1;
        union { us4 h; u64 q; } pk;
#pragma unroll
        for (int r = 0; r < 4; r++) {
            const float xv = bf2f((unsigned short)((xq >> (16 * r)) & 0xFFFFu));
            float s = z[r] + xv;
            s = fminf(fmaxf(s, -15.f), 15.f);
            const float e = __expf(2.f * s);
            pk.h[r] = f2bf(1.f - __fdividef(2.f, e + 1.f));
        }
        asm volatile("global_store_dwordx2 %0, %1, off sc0 sc1" :: "v"(hwr), "v"(pk.q) : "memory");
        asm volatile("s_waitcnt vmcnt(0)" ::: "memory");          // data at coherence point
        SB0;
        if (t < 1023) {
            if (l == 0)
                asm volatile("global_store_byte %0, %1, off sc0 sc1"
                             :: "v"(twr), "v"(one) : "memory");   // release tag (row t+1)
            twr += 128;
        }
        hrd += 65536; hwr += 65536;
        xq = xqn;
    }
}

// ---------- fused add-x + LayerNorm, one wave per row ----------
__global__ __launch_bounds__(256) void ln_ker(const unsigned short* __restrict__ y,
                                              const float* __restrict__ x,
                                              const float* __restrict__ gamma,
                                              const float* __restrict__ beta,
                                              float* __restrict__ out) {
    const int row = (blockIdx.x << 2) + (threadIdx.x >> 6);
    const int l = threadIdx.x & 63;
    const unsigned short* yr = y + (size_t)row * 1024;
    const float* xr = x + (size_t)row * 1024;
    float v[16];
    float s = 0.f, s2 = 0.f;
#pragma unroll
    for (int j = 0; j < 4; j++) {
        const int e = ((j << 6) + l) << 2;
        f4v xv = *(const f4v*)(xr + e);
        us4 yv = *(const us4*)(yr + e);
#pragma unroll
        for (int i = 0; i < 4; i++) {
            float t = xv[i] + bf2f(yv[i]);
            v[(j << 2) + i] = t; s += t; s2 += t * t;
        }
    }
#pragma unroll
    for (int off = 1; off < 64; off <<= 1) {
        s += __shfl_xor(s, off, 64);
        s2 += __shfl_xor(s2, off, 64);
    }
    const float mu = s * (1.f / 1024.f);
    const float var = fmaxf(s2 * (1.f / 1024.f) - mu * mu, 0.f);
    const float rs = rsqrtf(var + 1e-5f);
#pragma unroll
    for (int j = 0; j < 4; j++) {
        const int e = ((j << 6) + l) << 2;
        f4v g = *(const f4v*)(gamma + e);
        f4v bt = *(const f4v*)(beta + e);
        f4v o;
#pragma unroll
        for (int i = 0; i < 4; i++) o[i] = (v[(j << 2) + i] - mu) * rs * g[i] + bt[i];
        *(f4v*)(out + (size_t)row * 1024 + e) = o;
    }
}

// ---------- launch ----------
extern "C" void kernel_launch(void* const* d_in, const int* in_sizes, int n_in,
                              void* d_out, int out_size, void* d_ws, size_t ws_size,
                              hipStream_t stream) {
    const float* x = (const float*)d_in[0];
    const float* Amat = (const float*)d_in[1];
    const float* Bmat = (const float*)d_in[2];
    const float* Cmat = (const float*)d_in[3];
    const float* gamma = (const float*)d_in[4];
    const float* beta = (const float*)d_in[5];
    float* out = (float*)d_out;
    char* ws = (char*)d_ws;

    // layout (bytes):
    //   R1 = 0          : hs[1025][32][1024] bf16 (67,174,400) ; first 64MiB = xbf in phase 1
    //   R2 = 67,174,400 : xb (phase 1/2) -> y tmp (phase 3), 64 MiB
    //   OA              : A bf16 (2 MiB)
    //   OB              : B bf16 (2 MiB); first 128 KiB reused as packed byte tags after GEMM1
    //   OC              : C bf16 (2 MiB)
    const size_t R1 = 0;
    const size_t R2 = 67174400;
    const size_t OA = R2 + 67108864;
    const size_t OB = OA + 2097152;
    const size_t OC = OB + 2097152;
    const size_t END = OC + 2097152;
    if (ws_size < END) return;

    unsigned short* hsb = (unsigned short*)(ws + R1);       // hs base (slot 0 = h0)
    unsigned short* xbf = (unsigned short*)(ws + R1);       // x bf16 (phase 1 alias)
    unsigned short* xbb = (unsigned short*)(ws + R2);
    unsigned short* tmp = (unsigned short*)(ws + R2);
    unsigned short* Ab = (unsigned short*)(ws + OA);
    unsigned short* Bb = (unsigned short*)(ws + OB);
    unsigned short* Cb = (unsigned short*)(ws + OC);
    unsigned char* tags = (unsigned char*)(ws + OB);        // alias over dead B bf16

    cvt_ker<<<16384, 256, 0, stream>>>(x, xbf, 4194304);    // x -> bf16
    cvt_ker<<<512, 256, 0, stream>>>(Amat, Ab, 131072);
    cvt_ker<<<512, 256, 0, stream>>>(Bmat, Bb, 131072);
    cvt_ker<<<512, 256, 0, stream>>>(Cmat, Cb, 131072);

    // xb[b][s][e] = sum_d x[b][s][d]*B[e][d]
    gemm_bt<<<2048, 256, 0, stream>>>(xbf, Bb, xbb, 32768, 1024, 1024, 0);

    // zero h0 slot and packed tags (rows 0..1023, 128 B each)
    hipMemsetAsync(ws + R1, 0, 65536, stream);
    hipMemsetAsync(ws + OB, 0, 131072, stream);

    // sequential recurrence; writes hs[t+1][b][d]
    scan_ker<<<64, 128, 0, stream>>>(Ab, xbb, hsb, tags);

    // y rows (t*32+b) <- hs[t+1][b][:], output permuted to tmp[b][t][e]
    gemm_bt<<<2048, 256, 0, stream>>>(hsb + 32768, Cb, tmp, 32768, 1024, 1024, 1);

    // out = LN(y + x)
    ln_ker<<<8192, 256, 0, stream>>>(tmp, x, gamma, beta, out);
}